// Round 1
// baseline (189.052 us; speedup 1.0000x reference)
//
#include <hip/hip_runtime.h>
#include <stdint.h>

#define LL 2048
#define EE 1024
#define HH 16
#define DD 64
#define KX 1056   // 1024 + 16 (Sp*Mabs) + 16 (s*Mrel)

using short8 = __attribute__((ext_vector_type(8))) short;
using f32x4  = __attribute__((ext_vector_type(4))) float;

__device__ __forceinline__ short f2bf(float x) {
  union { float f; uint32_t u; } v; v.f = x;
  uint32_t r = v.u + 0x7fffu + ((v.u >> 16) & 1u);
  return (short)(r >> 16);
}

// ---- f32 -> bf16 convert, optional strided destination rows ----
__global__ __launch_bounds__(256) void convk(const float* __restrict__ src,
                                             short* __restrict__ dst,
                                             int n, int rowLen, int dstStride) {
  int i = (blockIdx.x * 256 + threadIdx.x) * 4;
  if (i >= n) return;
  const float4 v = *(const float4*)(src + i);
  int di = (rowLen == dstStride) ? i : (i / rowLen) * dstStride + (i % rowLen);
  union { short s[4]; uint64_t u; } p;
  p.s[0] = f2bf(v.x); p.s[1] = f2bf(v.y); p.s[2] = f2bf(v.z); p.s[3] = f2bf(v.w);
  *(uint64_t*)(dst + di) = p.u;
}

// ---- u[s][h][c] = sum_d Wq[h*64+d][c] * w_s[h*64+d]   (s=0: W_k_abs, s=1: W_k_rel) ----
__global__ __launch_bounds__(256) void uker(const float* __restrict__ Wq,
                                            const float* __restrict__ wabs,
                                            const float* __restrict__ wrel,
                                            float* __restrict__ u) {
  int flat = blockIdx.x * 256 + threadIdx.x;   // [0, 32768)
  int c = flat & (EE - 1);
  int h = (flat >> 10) & (HH - 1);
  int s = flat >> 14;
  const float* w = s ? wrel : wabs;
  float acc = 0.f;
  #pragma unroll 8
  for (int d = 0; d < DD; ++d)
    acc += Wq[(size_t)(h * DD + d) * EE + c] * w[h * DD + d];
  u[flat] = acc;
}

// ---- qaw[i][h] = qa (exact fp32), qaw[i][16+h] = qw ----
__global__ __launch_bounds__(256) void qawker(const float* __restrict__ Q,
                                              const float* __restrict__ u,
                                              float* __restrict__ qaw) {
  int i = blockIdx.x;
  int t = threadIdx.x;
  int h = t >> 4, seg = t & 15;
  const float* u0 = u + (size_t)h * EE;
  const float* u1 = u + (size_t)HH * EE + (size_t)h * EE;
  const float* q = Q + (size_t)i * EE;
  float a0 = 0.f, a1 = 0.f;
  for (int cc = 0; cc < 64; ++cc) {
    int c = cc * 16 + seg;
    float qv = q[c];
    a0 += qv * u0[c];
    a1 += qv * u1[c];
  }
  #pragma unroll
  for (int m = 1; m < 16; m <<= 1) {
    a0 += __shfl_xor(a0, m);
    a1 += __shfl_xor(a1, m);
  }
  if (seg == 0) { qaw[i * 32 + h] = a0; qaw[i * 32 + 16 + h] = a1; }
}

// ---- W2 tail columns: Mabs[h,n], Mrel[h,n] folded weights ----
__global__ __launch_bounds__(256) void mrelker(const float* __restrict__ Wout,
                                               const float* __restrict__ wva,
                                               const float* __restrict__ wvr,
                                               short* __restrict__ W2) {
  int flat = blockIdx.x * 256 + threadIdx.x;  // [0, 32768)
  int n = flat >> 5;
  int s = (flat >> 4) & 1;
  int h = flat & 15;
  const float* w = s ? wvr : wva;
  float acc = 0.f;
  #pragma unroll 8
  for (int d = 0; d < DD; ++d)
    acc += Wout[(size_t)n * EE + h * DD + d] * w[h * DD + d];
  W2[(size_t)n * KX + 1024 + s * 16 + h] = f2bf(acc);
}

// ---- GEMM: C[m][n] = sum_k A[m][k] * B[n][k]  (both K-contiguous, bf16 MFMA) ----
// z-batched. bf16Out + optional transposed store (for vpT); else fp32 out + bias.
__global__ __launch_bounds__(256) void gemm_bt(
    const short* __restrict__ Aall, const short* __restrict__ Ball,
    void* __restrict__ Call,
    int K, int aBatch, int bBatch, int cBatch,
    int ldc, int vTransZ, int ldcT, int bf16Out,
    const float* __restrict__ bias)
{
  const int BM = 64, BN = 128, BK = 32, PAD = 8;
  __shared__ short As[BM][BK + PAD];
  __shared__ short Bs[BN][BK + PAD];
  int z = blockIdx.z;
  const short* A = Aall + (size_t)z * aBatch;
  const short* B = Ball + (size_t)z * bBatch;
  int m0 = blockIdx.y * BM, n0 = blockIdx.x * BN;
  int t = threadIdx.x;
  int lane = t & 63, wave = t >> 6;
  int wm = wave >> 1, wn = wave & 1;          // 2x2 wave grid; wave tile 32x64
  int fr = lane & 15, fo = (lane >> 4) * 8;
  const f32x4 vzero = {0.f, 0.f, 0.f, 0.f};
  f32x4 acc[2][4];
  #pragma unroll
  for (int i = 0; i < 2; ++i)
    #pragma unroll
    for (int j = 0; j < 4; ++j) acc[i][j] = vzero;

  int kTiles = K / BK;
  for (int kt = 0; kt < kTiles; ++kt) {
    __syncthreads();
    {
      int row = t >> 2, kb = (t & 3) * 8;
      *(short8*)&As[row][kb] =
          *(const short8*)(A + (size_t)(m0 + row) * K + kt * BK + kb);
      *(short8*)&Bs[row][kb] =
          *(const short8*)(B + (size_t)(n0 + row) * K + kt * BK + kb);
      int u = t + 256;
      int row2 = u >> 2, kb2 = (u & 3) * 8;
      *(short8*)&Bs[row2][kb2] =
          *(const short8*)(B + (size_t)(n0 + row2) * K + kt * BK + kb2);
    }
    __syncthreads();
    short8 af[2], bfr[4];
    #pragma unroll
    for (int i = 0; i < 2; ++i) af[i] = *(const short8*)&As[wm * 32 + i * 16 + fr][fo];
    #pragma unroll
    for (int j = 0; j < 4; ++j) bfr[j] = *(const short8*)&Bs[wn * 64 + j * 16 + fr][fo];
    #pragma unroll
    for (int i = 0; i < 2; ++i)
      #pragma unroll
      for (int j = 0; j < 4; ++j)
        acc[i][j] = __builtin_amdgcn_mfma_f32_16x16x32_bf16(af[i], bfr[j], acc[i][j], 0, 0, 0);
  }

  int rb = (lane >> 4) * 4;
  bool doTrans = (z == vTransZ);
  #pragma unroll
  for (int i = 0; i < 2; ++i) {
    #pragma unroll
    for (int j = 0; j < 4; ++j) {
      int n = n0 + wn * 64 + j * 16 + fr;
      float bv = bias ? bias[n] : 0.f;
      #pragma unroll
      for (int r = 0; r < 4; ++r) {
        int m = m0 + wm * 32 + i * 16 + rb + r;
        float val = acc[i][j][r] + bv;
        if (bf16Out) {
          short* C = (short*)Call + (size_t)z * cBatch;
          if (doTrans) C[(size_t)n * ldcT + m] = f2bf(val);
          else         C[(size_t)m * ldc + n] = f2bf(val);
        } else {
          float* C = (float*)Call;
          C[(size_t)m * ldc + n] = val;
        }
      }
    }
  }
}

// ---- flash attention: per (head, 64 q-rows) block, 4 waves x 16 rows ----
__global__ __launch_bounds__(256) void flash(
    const short* __restrict__ qp, const short* __restrict__ kp,
    const short* __restrict__ vpT, const float* __restrict__ qaw,
    short* __restrict__ X2)
{
  const int KB = 64, QB = 64;
  __shared__ short k_lds[64][72];          // [key][d]
  __shared__ short v_lds[64][72];          // [d][key]
  __shared__ short p_lds[4][16][72];       // per-wave P scratch [i][key]
  int h = blockIdx.y;
  int q0 = blockIdx.x * QB;
  int t = threadIdx.x, wave = t >> 6, lane = t & 63;
  int fr = lane & 15, fo = (lane >> 4) * 8, rb = (lane >> 4) * 4;
  const f32x4 vzero = {0.f, 0.f, 0.f, 0.f};

  short8 qf[2];
  #pragma unroll
  for (int ks = 0; ks < 2; ++ks)
    qf[ks] = *(const short8*)(qp + (size_t)(q0 + wave * 16 + fr) * EE + h * 64 + ks * 32 + fo);

  const float LOG2E = 1.4426950408889634f;
  const float sc = LOG2E / 32.f;
  float qa_s[4], qw_s[4];
  #pragma unroll
  for (int r = 0; r < 4; ++r) {
    int gi = q0 + wave * 16 + rb + r;
    qa_s[r] = qaw[gi * 32 + h] * sc;
    qw_s[r] = qaw[gi * 32 + 16 + h] * (sc / 5000.f);
  }
  float m2[4], lsum[4] = {0,0,0,0}, SpA[4] = {0,0,0,0}, SrA[4] = {0,0,0,0};
  #pragma unroll
  for (int r = 0; r < 4; ++r) m2[r] = -1e30f;
  f32x4 Oa[4];
  #pragma unroll
  for (int fc = 0; fc < 4; ++fc) Oa[fc] = vzero;

  for (int k0 = 0; k0 < LL; k0 += KB) {
    __syncthreads();
    #pragma unroll
    for (int uu = 0; uu < 2; ++uu) {
      int u = t + uu * 256;
      int row = u >> 3, cb = (u & 7) * 8;
      *(short8*)&k_lds[row][cb] =
          *(const short8*)(kp + (size_t)(k0 + row) * EE + h * 64 + cb);
      *(short8*)&v_lds[row][cb] =
          *(const short8*)(vpT + (size_t)(h * 64 + row) * LL + k0 + cb);
    }
    __syncthreads();

    f32x4 S[4];
    #pragma unroll
    for (int jf = 0; jf < 4; ++jf) {
      f32x4 a = vzero;
      a = __builtin_amdgcn_mfma_f32_16x16x32_bf16(qf[0], *(const short8*)&k_lds[jf*16+fr][fo],      a, 0,0,0);
      a = __builtin_amdgcn_mfma_f32_16x16x32_bf16(qf[1], *(const short8*)&k_lds[jf*16+fr][32 + fo], a, 0,0,0);
      S[jf] = a;
    }

    float lg[4][4], tmax[4];
    #pragma unroll
    for (int r = 0; r < 4; ++r) tmax[r] = -1e30f;
    #pragma unroll
    for (int jf = 0; jf < 4; ++jf) {
      float jg = (float)(k0 + jf * 16 + fr);
      #pragma unroll
      for (int r = 0; r < 4; ++r) {
        float gi = (float)(q0 + wave * 16 + rb + r);
        float e2 = S[jf][r] * sc + jg * qa_s[r] + fabsf(gi - jg) * qw_s[r];
        lg[jf][r] = e2;
        tmax[r] = fmaxf(tmax[r], e2);
      }
    }
    #pragma unroll
    for (int r = 0; r < 4; ++r) {
      #pragma unroll
      for (int m = 1; m < 16; m <<= 1)
        tmax[r] = fmaxf(tmax[r], __shfl_xor(tmax[r], m));
      float mn = fmaxf(m2[r], tmax[r]);
      float alpha = exp2f(m2[r] - mn);
      m2[r] = mn;
      lsum[r] *= alpha; SpA[r] *= alpha; SrA[r] *= alpha;
      #pragma unroll
      for (int fc = 0; fc < 4; ++fc) Oa[fc][r] *= alpha;
    }
    #pragma unroll
    for (int jf = 0; jf < 4; ++jf) {
      float jg = (float)(k0 + jf * 16 + fr);
      #pragma unroll
      for (int r = 0; r < 4; ++r) {
        float gi = (float)(q0 + wave * 16 + rb + r);
        float p = exp2f(lg[jf][r] - m2[r]);
        lsum[r] += p;
        SpA[r] += p * jg;
        SrA[r] += p * (fabsf(gi - jg) * (1.f / 5000.f));
        p_lds[wave][rb + r][jf * 16 + fr] = f2bf(p);
      }
    }
    short8 pf0 = *(const short8*)&p_lds[wave][fr][fo];
    short8 pf1 = *(const short8*)&p_lds[wave][fr][32 + fo];
    #pragma unroll
    for (int fc = 0; fc < 4; ++fc) {
      Oa[fc] = __builtin_amdgcn_mfma_f32_16x16x32_bf16(pf0, *(const short8*)&v_lds[fc*16+fr][fo],      Oa[fc], 0,0,0);
      Oa[fc] = __builtin_amdgcn_mfma_f32_16x16x32_bf16(pf1, *(const short8*)&v_lds[fc*16+fr][32 + fo], Oa[fc], 0,0,0);
    }
  }

  #pragma unroll
  for (int r = 0; r < 4; ++r) {
    #pragma unroll
    for (int m = 1; m < 16; m <<= 1) {
      lsum[r] += __shfl_xor(lsum[r], m);
      SpA[r]  += __shfl_xor(SpA[r], m);
      SrA[r]  += __shfl_xor(SrA[r], m);
    }
  }
  float inv[4];
  #pragma unroll
  for (int r = 0; r < 4; ++r) inv[r] = 1.f / lsum[r];
  #pragma unroll
  for (int fc = 0; fc < 4; ++fc)
    #pragma unroll
    for (int r = 0; r < 4; ++r) {
      int gi = q0 + wave * 16 + rb + r;
      X2[(size_t)gi * KX + h * 64 + fc * 16 + fr] = f2bf(Oa[fc][r] * inv[r]);
    }
  if (fr == 0) {
    #pragma unroll
    for (int r = 0; r < 4; ++r) {
      int gi = q0 + wave * 16 + rb + r;
      X2[(size_t)gi * KX + 1024 + h] = f2bf(SpA[r] * inv[r]);
      X2[(size_t)gi * KX + 1040 + h] = f2bf(SrA[r] * inv[r]);
    }
  }
}

extern "C" void kernel_launch(void* const* d_in, const int* in_sizes, int n_in,
                              void* d_out, int out_size, void* d_ws, size_t ws_size,
                              hipStream_t stream) {
  const float* V    = (const float*)d_in[0];
  const float* Kin  = (const float*)d_in[1];
  const float* Q    = (const float*)d_in[2];
  // d_in[3] = position (== arange(L), used analytically)
  const float* Wq   = (const float*)d_in[4];
  const float* Wk   = (const float*)d_in[5];
  const float* Wv   = (const float*)d_in[6];
  const float* Wkr  = (const float*)d_in[7];
  const float* Wvr  = (const float*)d_in[8];
  const float* Wka  = (const float*)d_in[9];
  const float* Wva  = (const float*)d_in[10];
  const float* Wout = (const float*)d_in[11];
  const float* bout = (const float*)d_in[12];

  char* ws = (char*)d_ws;
  size_t off = 0;
  auto alloc = [&](size_t bytes) -> void* {
    void* p = ws + off;
    off = (off + bytes + 255) & ~(size_t)255;
    return p;
  };
  short* Qb  = (short*)alloc((size_t)LL * EE * 2);
  short* Kb  = (short*)alloc((size_t)LL * EE * 2);
  short* Vb  = (short*)alloc((size_t)LL * EE * 2);
  short* Wqb = (short*)alloc((size_t)EE * EE * 2);
  short* Wkb = (short*)alloc((size_t)EE * EE * 2);
  short* Wvb = (short*)alloc((size_t)EE * EE * 2);
  short* qp  = (short*)alloc((size_t)LL * EE * 2);
  short* kp  = (short*)alloc((size_t)LL * EE * 2);
  short* vpT = (short*)alloc((size_t)EE * LL * 2);
  short* W2  = (short*)alloc((size_t)EE * KX * 2);
  short* X2  = (short*)alloc((size_t)LL * KX * 2);
  float* u   = (float*)alloc((size_t)2 * HH * EE * 4);
  float* qaw = (float*)alloc((size_t)LL * 32 * 4);
  (void)Kb; (void)Vb; (void)Wkb; (void)Wvb; (void)kp; (void)vpT;
  (void)in_sizes; (void)n_in; (void)out_size; (void)ws_size;

  // 1) bf16 conversions
  convk<<<LL * EE / 1024, 256, 0, stream>>>(Q,    Qb,  LL * EE, EE, EE);
  convk<<<LL * EE / 1024, 256, 0, stream>>>(Kin,  Kb,  LL * EE, EE, EE);
  convk<<<LL * EE / 1024, 256, 0, stream>>>(V,    Vb,  LL * EE, EE, EE);
  convk<<<EE * EE / 1024, 256, 0, stream>>>(Wq,   Wqb, EE * EE, EE, EE);
  convk<<<EE * EE / 1024, 256, 0, stream>>>(Wk,   Wkb, EE * EE, EE, EE);
  convk<<<EE * EE / 1024, 256, 0, stream>>>(Wv,   Wvb, EE * EE, EE, EE);
  convk<<<EE * EE / 1024, 256, 0, stream>>>(Wout, W2,  EE * EE, EE, KX);

  // 2) exact fp32 rank-1 helpers
  uker<<<(2 * HH * EE) / 256, 256, 0, stream>>>(Wq, Wka, Wkr, u);
  qawker<<<LL, 256, 0, stream>>>(Q, u, qaw);
  mrelker<<<(EE * 32) / 256, 256, 0, stream>>>(Wout, Wva, Wvr, W2);

  // 3) projections: z=0 q, z=1 k, z=2 v (stored transposed [E][L])
  dim3 gp(EE / 128, LL / 64, 3);
  gemm_bt<<<gp, 256, 0, stream>>>(Qb, Wqb, qp, EE,
                                  LL * EE, EE * EE, LL * EE,
                                  EE, /*vTransZ=*/2, /*ldcT=*/LL, /*bf16Out=*/1, nullptr);

  // 4) flash attention -> X2[:, :1024] = attn@vp, X2[:,1024+h]=Sp, X2[:,1040+h]=s
  flash<<<dim3(LL / 64, HH), 256, 0, stream>>>(qp, kp, vpT, qaw, X2);

  // 5) final: d_out = X2 @ W2^T + b_out   (K = 1056 folds the rank-1 terms)
  dim3 go(EE / 128, LL / 64, 1);
  gemm_bt<<<go, 256, 0, stream>>>(X2, W2, d_out, KX,
                                  0, 0, 0,
                                  EE, /*vTransZ=*/-1, /*ldcT=*/1, /*bf16Out=*/0, bout);
}

// Round 2
// 155.055 us; speedup vs baseline: 1.2193x; 1.2193x over previous
//
#include <hip/hip_runtime.h>
#include <stdint.h>

#define LL 2048
#define EE 1024
#define HH 16
#define DD 64
#define KX 1056   // 1024 + 16 (Sp*Mabs) + 16 (s*Mrel)

using short8 = __attribute__((ext_vector_type(8))) short;
using s4v    = __attribute__((ext_vector_type(4))) short;
using f32x4  = __attribute__((ext_vector_type(4))) float;

#if __has_builtin(__builtin_amdgcn_mfma_f32_16x16x16_bf16)
#define MFMA16(a,b,c) __builtin_amdgcn_mfma_f32_16x16x16_bf16(a,b,c,0,0,0)
#elif __has_builtin(__builtin_amdgcn_mfma_f32_16x16x16bf16_1k)
#define MFMA16(a,b,c) __builtin_amdgcn_mfma_f32_16x16x16bf16_1k(a,b,c,0,0,0)
#else
static __device__ __forceinline__ f32x4 mfma16f(s4v a, s4v b, f32x4 c) {
  asm volatile("v_mfma_f32_16x16x16_bf16 %0, %1, %2, %0" : "+v"(c) : "v"(a), "v"(b));
  return c;
}
#define MFMA16(a,b,c) mfma16f(a,b,c)
#endif

__device__ __forceinline__ short f2bf(float x) {
  union { float f; uint32_t u; } v; v.f = x;
  uint32_t r = v.u + 0x7fffu + ((v.u >> 16) & 1u);
  return (short)(r >> 16);
}

// ---- fused f32 -> bf16 convert for all 7 tensors (one launch) ----
__global__ __launch_bounds__(256) void convall(
    const float* __restrict__ Q, const float* __restrict__ K,
    const float* __restrict__ V, const float* __restrict__ Wq,
    const float* __restrict__ Wk, const float* __restrict__ Wv,
    const float* __restrict__ Wout,
    short* __restrict__ Qb, short* __restrict__ Kb, short* __restrict__ Vb,
    short* __restrict__ Wqb, short* __restrict__ Wkb, short* __restrict__ Wvb,
    short* __restrict__ W2) {
  const int S1 = LL * EE / 4;   // 524288 float4 per activation
  const int SW = EE * EE / 4;   // 262144 float4 per weight
  int i4 = blockIdx.x * 256 + threadIdx.x;
  const float* src; short* dst; int idx4; bool strided = false;
  if (i4 < 3 * S1) {
    int z = i4 >> 19; idx4 = i4 & (S1 - 1);
    src = z == 0 ? Q : (z == 1 ? K : V);
    dst = z == 0 ? Qb : (z == 1 ? Kb : Vb);
  } else {
    int j = i4 - 3 * S1;
    int z = j >> 18; idx4 = j & (SW - 1);
    src = z == 0 ? Wq : (z == 1 ? Wk : (z == 2 ? Wv : Wout));
    dst = z == 0 ? Wqb : (z == 1 ? Wkb : (z == 2 ? Wvb : W2));
    strided = (z == 3);
  }
  int i = idx4 * 4;
  const float4 v = *(const float4*)(src + i);
  int di = strided ? ((i >> 10) * KX + (i & 1023)) : i;
  union { short s[4]; uint64_t u; } p;
  p.s[0] = f2bf(v.x); p.s[1] = f2bf(v.y); p.s[2] = f2bf(v.z); p.s[3] = f2bf(v.w);
  *(uint64_t*)(dst + di) = p.u;
}

// ---- u[s][h][c] = sum_d Wq[h*64+d][c] * w_s[h*64+d] ----
__global__ __launch_bounds__(256) void uker(const float* __restrict__ Wq,
                                            const float* __restrict__ wabs,
                                            const float* __restrict__ wrel,
                                            float* __restrict__ u) {
  int flat = blockIdx.x * 256 + threadIdx.x;
  int c = flat & (EE - 1);
  int h = (flat >> 10) & (HH - 1);
  int s = flat >> 14;
  const float* w = s ? wrel : wabs;
  float acc = 0.f;
  #pragma unroll 8
  for (int d = 0; d < DD; ++d)
    acc += Wq[(size_t)(h * DD + d) * EE + c] * w[h * DD + d];
  u[flat] = acc;
}

// ---- qaw[i][h] = qa (exact fp32), qaw[i][16+h] = qw ----
__global__ __launch_bounds__(256) void qawker(const float* __restrict__ Q,
                                              const float* __restrict__ u,
                                              float* __restrict__ qaw) {
  int i = blockIdx.x;
  int t = threadIdx.x;
  int h = t >> 4, seg = t & 15;
  const float* u0 = u + (size_t)h * EE;
  const float* u1 = u + (size_t)HH * EE + (size_t)h * EE;
  const float* q = Q + (size_t)i * EE;
  float a0 = 0.f, a1 = 0.f;
  for (int cc = 0; cc < 64; ++cc) {
    int c = cc * 16 + seg;
    float qv = q[c];
    a0 += qv * u0[c];
    a1 += qv * u1[c];
  }
  #pragma unroll
  for (int m = 1; m < 16; m <<= 1) {
    a0 += __shfl_xor(a0, m);
    a1 += __shfl_xor(a1, m);
  }
  if (seg == 0) { qaw[i * 32 + h] = a0; qaw[i * 32 + 16 + h] = a1; }
}

// ---- W2 tail columns: folded Wout @ w_v_abs / w_v_rel per head ----
__global__ __launch_bounds__(256) void mrelker(const float* __restrict__ Wout,
                                               const float* __restrict__ wva,
                                               const float* __restrict__ wvr,
                                               short* __restrict__ W2) {
  int flat = blockIdx.x * 256 + threadIdx.x;
  int n = flat >> 5;
  int s = (flat >> 4) & 1;
  int h = flat & 15;
  const float* w = s ? wvr : wva;
  float acc = 0.f;
  #pragma unroll 8
  for (int d = 0; d < DD; ++d)
    acc += Wout[(size_t)n * EE + h * DD + d] * w[h * DD + d];
  W2[(size_t)n * KX + 1024 + s * 16 + h] = f2bf(acc);
}

// ---- GEMM: C[m][n] = sum_k A[m][k] * B[n][k] ----
__global__ __launch_bounds__(256) void gemm_bt(
    const short* __restrict__ Aall, const short* __restrict__ Ball,
    void* __restrict__ Call,
    int K, int aBatch, int bBatch, int cBatch,
    int ldc, int vTransZ, int ldcT, int bf16Out,
    const float* __restrict__ bias, int scaleZ, float scaleVal)
{
  const int BM = 64, BN = 128, BK = 32, PAD = 8;
  __shared__ short As[BM][BK + PAD];
  __shared__ short Bs[BN][BK + PAD];
  int z = blockIdx.z;
  const short* A = Aall + (size_t)z * aBatch;
  const short* B = Ball + (size_t)z * bBatch;
  int m0 = blockIdx.y * BM, n0 = blockIdx.x * BN;
  int t = threadIdx.x;
  int lane = t & 63, wave = t >> 6;
  int wm = wave >> 1, wn = wave & 1;
  int fr = lane & 15, fo = (lane >> 4) * 8;
  const f32x4 vzero = {0.f, 0.f, 0.f, 0.f};
  f32x4 acc[2][4];
  #pragma unroll
  for (int i = 0; i < 2; ++i)
    #pragma unroll
    for (int j = 0; j < 4; ++j) acc[i][j] = vzero;

  int kTiles = K / BK;
  for (int kt = 0; kt < kTiles; ++kt) {
    __syncthreads();
    {
      int row = t >> 2, kb = (t & 3) * 8;
      *(short8*)&As[row][kb] =
          *(const short8*)(A + (size_t)(m0 + row) * K + kt * BK + kb);
      *(short8*)&Bs[row][kb] =
          *(const short8*)(B + (size_t)(n0 + row) * K + kt * BK + kb);
      int uu = t + 256;
      int row2 = uu >> 2, kb2 = (uu & 3) * 8;
      *(short8*)&Bs[row2][kb2] =
          *(const short8*)(B + (size_t)(n0 + row2) * K + kt * BK + kb2);
    }
    __syncthreads();
    short8 af[2], bfr[4];
    #pragma unroll
    for (int i = 0; i < 2; ++i) af[i] = *(const short8*)&As[wm * 32 + i * 16 + fr][fo];
    #pragma unroll
    for (int j = 0; j < 4; ++j) bfr[j] = *(const short8*)&Bs[wn * 64 + j * 16 + fr][fo];
    #pragma unroll
    for (int i = 0; i < 2; ++i)
      #pragma unroll
      for (int j = 0; j < 4; ++j)
        acc[i][j] = __builtin_amdgcn_mfma_f32_16x16x32_bf16(af[i], bfr[j], acc[i][j], 0, 0, 0);
  }

  int rb = (lane >> 4) * 4;
  bool doTrans = (z == vTransZ);
  bool doScale = (z == scaleZ);
  #pragma unroll
  for (int i = 0; i < 2; ++i) {
    #pragma unroll
    for (int j = 0; j < 4; ++j) {
      int n = n0 + wn * 64 + j * 16 + fr;
      float bv = bias ? bias[n] : 0.f;
      #pragma unroll
      for (int r = 0; r < 4; ++r) {
        int m = m0 + wm * 32 + i * 16 + rb + r;
        float val = acc[i][j][r];
        if (doScale) val *= scaleVal;
        val += bv;
        if (bf16Out) {
          short* C = (short*)Call + (size_t)z * cBatch;
          if (doTrans) C[(size_t)n * ldcT + m] = f2bf(val);
          else         C[(size_t)m * ldc + n] = f2bf(val);
        } else {
          float* C = (float*)Call;
          C[(size_t)m * ldc + n] = val;
        }
      }
    }
  }
}

// ---- flash attention, split-K(2), swapped-QK, in-register softmax ----
// Grid (LL/64, HH, 2). Writes unnormalized partials:
//   Opart[(half*HH+h)*LL + q][d]  (f32, 64 per row)
//   stats[(half*HH+h)*LL + q] = {m, l, Sp, Sr}  (f32x4)
__global__ __launch_bounds__(256, 4) void flash2(
    const short* __restrict__ qp, const short* __restrict__ kp,
    const short* __restrict__ vpT, const float* __restrict__ qaw,
    float* __restrict__ Opart, float* __restrict__ stats)
{
  const int KB = 64;
  __shared__ short k_lds[64][72];          // [key][d]
  __shared__ short v_lds[64][72];          // [d][key]
  int h = blockIdx.y;
  int q0 = blockIdx.x * 64;
  int half = blockIdx.z;
  int kbeg = half * 1024;
  int t = threadIdx.x, w = t >> 6, lane = t & 63;
  int g = lane >> 4, fr = lane & 15;
  int gi = q0 + w * 16 + fr;               // this lane's q-row (softmax state)
  float gif = (float)gi;
  const f32x4 vzero = {0.f, 0.f, 0.f, 0.f};

  // Q fragment (B-operand of swapped QK). qp already scaled by log2e/32.
  short8 qf[2];
  #pragma unroll
  for (int ks = 0; ks < 2; ++ks)
    qf[ks] = *(const short8*)(qp + (size_t)gi * EE + h * 64 + ks * 32 + g * 8);

  const float LOG2E = 1.4426950408889634f;
  const float sc = LOG2E / 32.f;
  float qa_s = qaw[gi * 32 + h] * sc;
  float qw_s = qaw[gi * 32 + 16 + h] * (sc / 5000.f);

  float m2 = -1e30f, lsum = 0.f, SpA = 0.f, SrA = 0.f;
  f32x4 Oa[4];
  #pragma unroll
  for (int fc = 0; fc < 4; ++fc) Oa[fc] = vzero;

  for (int kt = 0; kt < 16; ++kt) {
    int k0 = kbeg + kt * KB;
    __syncthreads();
    #pragma unroll
    for (int uu = 0; uu < 2; ++uu) {
      int u2 = t + uu * 256;
      int row = u2 >> 3, cb = (u2 & 7) * 8;
      *(short8*)&k_lds[row][cb] =
          *(const short8*)(kp + (size_t)(k0 + row) * EE + h * 64 + cb);
      *(short8*)&v_lds[row][cb] =
          *(const short8*)(vpT + (size_t)(h * 64 + row) * LL + k0 + cb);
    }
    __syncthreads();

    // S^T[j][q] = mfma(K_frag, Q_frag): lane holds q=fr, j = k0+jt*16+4g+r
    f32x4 St[4];
    #pragma unroll
    for (int jt = 0; jt < 4; ++jt) {
      f32x4 a = vzero;
      a = __builtin_amdgcn_mfma_f32_16x16x32_bf16(
              *(const short8*)&k_lds[jt * 16 + fr][g * 8], qf[0], a, 0, 0, 0);
      a = __builtin_amdgcn_mfma_f32_16x16x32_bf16(
              *(const short8*)&k_lds[jt * 16 + fr][32 + g * 8], qf[1], a, 0, 0, 0);
      St[jt] = a;
    }

    // logits (exp2 domain), per-lane row max
    float pf[4][4];
    float tm = -1e30f;
    #pragma unroll
    for (int jt = 0; jt < 4; ++jt) {
      float jb = (float)(k0 + jt * 16 + 4 * g);
      #pragma unroll
      for (int r = 0; r < 4; ++r) {
        float jgf = jb + (float)r;
        float e = St[jt][r] + jgf * qa_s + fabsf(gif - jgf) * qw_s;
        pf[jt][r] = e;
        tm = fmaxf(tm, e);
      }
    }
    tm = fmaxf(tm, __shfl_xor(tm, 16));
    tm = fmaxf(tm, __shfl_xor(tm, 32));

    // deferred rescale (THR=8): p bounded by 2^8
    if (__any(tm > m2 + 8.f)) {
      float mn = fmaxf(m2, tm);
      float alpha = exp2f(m2 - mn);
      m2 = mn;
      lsum *= alpha; SpA *= alpha; SrA *= alpha;
      #pragma unroll
      for (int r = 0; r < 4; ++r) {
        float alr = __shfl(alpha, ((lane >> 4) << 2) + r);  // alpha of row 4g+r
        #pragma unroll
        for (int fc = 0; fc < 4; ++fc) Oa[fc][r] *= alr;
      }
    }

    float Pt = 0.f, Spt = 0.f;
    #pragma unroll
    for (int jt = 0; jt < 4; ++jt) {
      float jb = (float)(k0 + jt * 16 + 4 * g);
      #pragma unroll
      for (int r = 0; r < 4; ++r) {
        float p = exp2f(pf[jt][r] - m2);
        pf[jt][r] = p;
        Pt += p;
        Spt = fmaf(p, jb + (float)r, Spt);
      }
    }
    lsum += Pt; SpA += Spt;
    if (gi >= k0 + KB)      SrA += gif * Pt - Spt;
    else if (gi < k0)       SrA += Spt - gif * Pt;
    else {
      #pragma unroll
      for (int jt = 0; jt < 4; ++jt) {
        float jb = (float)(k0 + jt * 16 + 4 * g);
        #pragma unroll
        for (int r = 0; r < 4; ++r)
          SrA += pf[jt][r] * fabsf(gif - (jb + (float)r));
      }
    }

    // pack P to bf16 in-register: pa[jt] = P[q=fr][j = jt*16+4g .. +3]
    s4v pa[4];
    #pragma unroll
    for (int jt = 0; jt < 4; ++jt) {
      int lo, hi;
      asm("v_cvt_pk_bf16_f32 %0, %1, %2" : "=v"(lo) : "v"(pf[jt][0]), "v"(pf[jt][1]));
      asm("v_cvt_pk_bf16_f32 %0, %1, %2" : "=v"(hi) : "v"(pf[jt][2]), "v"(pf[jt][3]));
      union { int i[2]; s4v s; } uu; uu.i[0] = lo; uu.i[1] = hi;
      pa[jt] = uu.s;
    }

    // PV: O[q][d] += P * V, K=16 mfma per jt tile; V^T fragment from LDS
    #pragma unroll
    for (int jt = 0; jt < 4; ++jt) {
      #pragma unroll
      for (int fc = 0; fc < 4; ++fc) {
        s4v vb = *(const s4v*)&v_lds[fc * 16 + fr][jt * 16 + 4 * g];
        Oa[fc] = MFMA16(pa[jt], vb, Oa[fc]);
      }
    }
  }

  // reduce lane-partials across the 4 groups (per q-row fr)
  lsum += __shfl_xor(lsum, 16); lsum += __shfl_xor(lsum, 32);
  SpA  += __shfl_xor(SpA, 16);  SpA  += __shfl_xor(SpA, 32);
  SrA  += __shfl_xor(SrA, 16);  SrA  += __shfl_xor(SrA, 32);

  size_t sb = (size_t)(half * HH + h) * LL;
  if (g == 0) {
    float4 s4 = {m2, lsum, SpA, SrA};
    *(float4*)&stats[(sb + q0 + w * 16 + fr) * 4] = s4;
  }
  // Oa[fc][r] = O[q = q0+w*16+4g+r][d = fc*16+fr] (unnormalized)
  #pragma unroll
  for (int fc = 0; fc < 4; ++fc)
    #pragma unroll
    for (int r = 0; r < 4; ++r)
      Opart[(sb + q0 + w * 16 + 4 * g + r) * 64 + fc * 16 + fr] = Oa[fc][r];
}

// ---- merge the two K-halves, normalize, emit X2 (bf16, KX columns) ----
__global__ __launch_bounds__(256) void merge(const float* __restrict__ Opart,
                                             const float* __restrict__ stats,
                                             short* __restrict__ X2) {
  int q = blockIdx.x;
  int t = threadIdx.x;
  int h = t >> 4, ds = (t & 15) * 4;
  const float4 s0 = *(const float4*)&stats[((size_t)h * LL + q) * 4];
  const float4 s1 = *(const float4*)&stats[((size_t)(HH + h) * LL + q) * 4];
  float m = fmaxf(s0.x, s1.x);
  float a0 = exp2f(s0.x - m), a1 = exp2f(s1.x - m);
  float inv = 1.f / (s0.y * a0 + s1.y * a1);
  const float4 O0 = *(const float4*)&Opart[((size_t)h * LL + q) * 64 + ds];
  const float4 O1 = *(const float4*)&Opart[((size_t)(HH + h) * LL + q) * 64 + ds];
  union { short s[4]; uint64_t u; } pk;
  pk.s[0] = f2bf((O0.x * a0 + O1.x * a1) * inv);
  pk.s[1] = f2bf((O0.y * a0 + O1.y * a1) * inv);
  pk.s[2] = f2bf((O0.z * a0 + O1.z * a1) * inv);
  pk.s[3] = f2bf((O0.w * a0 + O1.w * a1) * inv);
  *(uint64_t*)&X2[(size_t)q * KX + h * 64 + ds] = pk.u;
  if (t < 32) {
    int hh = t & 15;
    const float4 t0 = *(const float4*)&stats[((size_t)hh * LL + q) * 4];
    const float4 t1 = *(const float4*)&stats[((size_t)(HH + hh) * LL + q) * 4];
    float mm = fmaxf(t0.x, t1.x);
    float b0 = exp2f(t0.x - mm), b1 = exp2f(t1.x - mm);
    float linv = 1.f / (t0.y * b0 + t1.y * b1);
    float val = (t < 16) ? (t0.z * b0 + t1.z * b1) * linv
                         : (t0.w * b0 + t1.w * b1) * linv * (1.f / 5000.f);
    X2[(size_t)q * KX + 1024 + (t < 16 ? hh : 16 + hh)] = f2bf(val);
  }
}

extern "C" void kernel_launch(void* const* d_in, const int* in_sizes, int n_in,
                              void* d_out, int out_size, void* d_ws, size_t ws_size,
                              hipStream_t stream) {
  const float* V    = (const float*)d_in[0];
  const float* Kin  = (const float*)d_in[1];
  const float* Q    = (const float*)d_in[2];
  const float* Wq   = (const float*)d_in[4];
  const float* Wk   = (const float*)d_in[5];
  const float* Wv   = (const float*)d_in[6];
  const float* Wkr  = (const float*)d_in[7];
  const float* Wvr  = (const float*)d_in[8];
  const float* Wka  = (const float*)d_in[9];
  const float* Wva  = (const float*)d_in[10];
  const float* Wout = (const float*)d_in[11];
  const float* bout = (const float*)d_in[12];

  char* ws = (char*)d_ws;
  size_t off = 0;
  auto alloc = [&](size_t bytes) -> void* {
    void* p = ws + off;
    off = (off + bytes + 255) & ~(size_t)255;
    return p;
  };
  short* Qb  = (short*)alloc((size_t)LL * EE * 2);   // ┐ overlay region (18 MB):
  short* Kb  = (short*)alloc((size_t)LL * EE * 2);   // │ dead after proj gemm;
  short* Vb  = (short*)alloc((size_t)LL * EE * 2);   // │ reused as Opart+stats
  short* Wqb = (short*)alloc((size_t)EE * EE * 2);   // │ by flash2/merge
  short* Wkb = (short*)alloc((size_t)EE * EE * 2);   // │
  short* Wvb = (short*)alloc((size_t)EE * EE * 2);   // ┘
  short* qp  = (short*)alloc((size_t)LL * EE * 2);
  short* kp  = (short*)alloc((size_t)LL * EE * 2);
  short* vpT = (short*)alloc((size_t)EE * LL * 2);
  short* W2  = (short*)alloc((size_t)EE * KX * 2);
  short* X2  = (short*)alloc((size_t)LL * KX * 2);
  float* u   = (float*)alloc((size_t)2 * HH * EE * 4);
  float* qaw = (float*)alloc((size_t)LL * 32 * 4);
  float* Opart = (float*)Qb;                                   // 16 MB
  float* stats = (float*)((char*)Qb + (size_t)17 * 1024 * 1024); // 1 MB
  (void)in_sizes; (void)n_in; (void)out_size; (void)ws_size;

  const float sc = 1.4426950408889634f / 32.f;

  // 1) all bf16 conversions in one launch
  convall<<<(3 * LL * EE / 4 + 4 * EE * EE / 4) / 256, 256, 0, stream>>>(
      Q, Kin, V, Wq, Wk, Wv, Wout, Qb, Kb, Vb, Wqb, Wkb, Wvb, W2);

  // 2) exact fp32 rank-1 helpers
  uker<<<(2 * HH * EE) / 256, 256, 0, stream>>>(Wq, Wka, Wkr, u);
  qawker<<<LL, 256, 0, stream>>>(Q, u, qaw);
  mrelker<<<(EE * 32) / 256, 256, 0, stream>>>(Wout, Wva, Wvr, W2);

  // 3) projections: z=0 q (scaled by log2e/32), z=1 k, z=2 v (transposed)
  dim3 gp(EE / 128, LL / 64, 3);
  gemm_bt<<<gp, 256, 0, stream>>>(Qb, Wqb, qp, EE,
                                  LL * EE, EE * EE, LL * EE,
                                  EE, /*vTransZ=*/2, /*ldcT=*/LL, /*bf16Out=*/1,
                                  nullptr, /*scaleZ=*/0, sc);

  // 4) split-K flash attention -> fp32 partials
  flash2<<<dim3(LL / 64, HH, 2), 256, 0, stream>>>(qp, kp, vpT, qaw, Opart, stats);

  // 5) merge halves -> X2 (bf16, 1056 cols incl Sp/s tails)
  merge<<<LL, 256, 0, stream>>>(Opart, stats, X2);

  // 6) final: d_out = X2 @ W2^T + b_out
  dim3 go(EE / 128, LL / 64, 1);
  gemm_bt<<<go, 256, 0, stream>>>(X2, W2, d_out, KX,
                                  0, 0, 0,
                                  EE, /*vTransZ=*/-1, /*ldcT=*/1, /*bf16Out=*/0,
                                  bout, /*scaleZ=*/-1, 1.f);
}